// Round 1
// 776.261 us; speedup vs baseline: 1.0026x; 1.0026x over previous
//
#include <hip/hip_runtime.h>
#include <hip/hip_fp16.h>

#define F_IN 512
#define SCAN_B 1024

// --- in-degree count over col (int atomics) ---
__global__ void k_deg(const int* __restrict__ col, int* __restrict__ deg, int E) {
    int i = blockIdx.x * blockDim.x + threadIdx.x;
    if (i < E) atomicAdd(&deg[col[i]], 1);
}

// --- per-block inclusive scan of deg -> exclusive ptr + block sums; also dinv ---
__global__ void k_scan1(const int* __restrict__ deg, int* __restrict__ ptr,
                        int* __restrict__ bsum, float* __restrict__ dinv, int n)
{
    __shared__ int tmp[SCAN_B];
    int tid = threadIdx.x;
    int i = blockIdx.x * SCAN_B + tid;
    int v = (i < n) ? deg[i] : 0;
    if (i < n) dinv[i] = rsqrtf((float)(v + 1));   // +1 self-loop
    tmp[tid] = v;
    __syncthreads();
    for (int off = 1; off < SCAN_B; off <<= 1) {
        int t = (tid >= off) ? tmp[tid - off] : 0;
        __syncthreads();
        tmp[tid] += t;
        __syncthreads();
    }
    if (i < n) ptr[i] = tmp[tid] - v;              // exclusive within block
    if (tid == SCAN_B - 1) bsum[blockIdx.x] = tmp[tid];
}

// --- exclusive scan of block sums (nb <= 128) ---
__global__ void k_scan2(int* __restrict__ bsum, int nb)
{
    __shared__ int tmp[128];
    int tid = threadIdx.x;
    int v = (tid < nb) ? bsum[tid] : 0;
    tmp[tid] = v;
    __syncthreads();
    for (int off = 1; off < 128; off <<= 1) {
        int t = (tid >= off) ? tmp[tid - off] : 0;
        __syncthreads();
        tmp[tid] += t;
        __syncthreads();
    }
    if (tid < nb) bsum[tid] = tmp[tid] - v;
}

// --- add block offsets -> global exclusive prefix ---
__global__ void k_scan3(int* __restrict__ ptr, const int* __restrict__ bsum, int n)
{
    int i = blockIdx.x * SCAN_B + threadIdx.x;
    if (i < n) ptr[i] += bsum[blockIdx.x];
}

// --- CSR fill: csr[slot in col-bucket] = row.  After this, ptr[c] = inclusive end. ---
__global__ void k_fill(const int* __restrict__ row, const int* __restrict__ col,
                       int* __restrict__ ptr, int* __restrict__ csr, int E)
{
    int e = blockIdx.x * blockDim.x + threadIdx.x;
    if (e < E) {
        int c = col[e];
        int p = atomicAdd(&ptr[c], 1);
        csr[p] = row[e];
    }
}

// --- hs = (x @ W1) * dinv[node] stored f16 ---
// wave-per-node; W1 (512x16) in 128 VGPRs/lane; LDS transpose-reduce.
__global__ __launch_bounds__(256) void k_gemm1(
    const float* __restrict__ x, const float* __restrict__ W1,
    const float* __restrict__ dinv, __half2* __restrict__ hs, int n)
{
    __shared__ float red[4][64 * 17];       // pad 17: 2-way bank alias = free
    const int lane = threadIdx.x & 63;
    const int wib  = threadIdx.x >> 6;
    const int wave = blockIdx.x * (blockDim.x >> 6) + wib;
    const int nw   = gridDim.x * (blockDim.x >> 6);
    float* rb = red[wib];

    float w[128];
    #pragma unroll
    for (int i = 0; i < 32; ++i) {
        float4 t = ((const float4*)W1)[lane * 32 + i];
        w[4*i+0] = t.x; w[4*i+1] = t.y; w[4*i+2] = t.z; w[4*i+3] = t.w;
    }
    const int q  = lane >> 4;
    const int jj = lane & 15;

    for (int node = wave; node < n; node += nw) {
        const float4* xr = (const float4*)(x + (size_t)node * F_IN);
        float4 a = xr[lane * 2];
        float4 b = xr[lane * 2 + 1];
        float xs[8] = {a.x, a.y, a.z, a.w, b.x, b.y, b.z, b.w};

        float p[16];
        #pragma unroll
        for (int j = 0; j < 16; ++j) p[j] = 0.f;
        #pragma unroll
        for (int i = 0; i < 8; ++i)
            #pragma unroll
            for (int j = 0; j < 16; ++j)
                p[j] = fmaf(xs[i], w[i * 16 + j], p[j]);

        #pragma unroll
        for (int j = 0; j < 16; ++j) rb[lane * 17 + j] = p[j];
        __asm__ volatile("s_waitcnt lgkmcnt(0)" ::: "memory");
        float s = 0.f;
        #pragma unroll
        for (int i = 0; i < 16; ++i) s += rb[(q * 16 + i) * 17 + jj];
        s += __shfl_down(s, 32);
        s += __shfl_down(s, 16);

        float di = dinv[node];
        float sv = s * di;
        float sn = __shfl_down(sv, 1);      // lanes 0..14 read active lanes 1..15
        if (lane < 16 && (lane & 1) == 0) {
            __half2 hv = __halves2half2(__float2half(sv), __float2half(sn));
            hs[node * 8 + (lane >> 1)] = hv;
        }
    }
}

// --- gather layer-1 + fused gemm2: 16 lanes/node, fp32 accumulate, no atomics ---
// sum = hs[self] + sum_{e in CSR(node)} hs[src]; v = relu(sum*di + b1);
// hs2 = (v @ W2) * di, f16.
__global__ __launch_bounds__(256) void k_agg1(
    const __half* __restrict__ hs, const int* __restrict__ ptr,
    const int* __restrict__ csr, const float* __restrict__ dinv,
    const float* __restrict__ b1, const float* __restrict__ W2,
    __half2* __restrict__ hs2, int n)
{
    int t = blockIdx.x * blockDim.x + threadIdx.x;
    int node = t >> 4, j = t & 15;
    if (node >= n) return;
    int s0 = node ? ptr[node - 1] : 0;
    int s1 = ptr[node];
    float sum = __half2float(hs[node * 16 + j]);     // self-loop
    int e = s0;
    for (; e + 4 <= s1; e += 4) {                    // 4 independent load chains
        int a0 = csr[e], a1 = csr[e+1], a2 = csr[e+2], a3 = csr[e+3];
        float v0 = __half2float(hs[a0 * 16 + j]);
        float v1 = __half2float(hs[a1 * 16 + j]);
        float v2 = __half2float(hs[a2 * 16 + j]);
        float v3 = __half2float(hs[a3 * 16 + j]);
        sum += (v0 + v1) + (v2 + v3);
    }
    for (; e < s1; ++e) sum += __half2float(hs[csr[e] * 16 + j]);

    float di = dinv[node];
    float v = fmaxf(fmaf(sum, di, b1[j]), 0.f);
    float h2 = 0.f;
    #pragma unroll
    for (int k = 0; k < 16; ++k) {
        float ok = __shfl(v, k, 16);
        h2 = fmaf(ok, W2[k * 16 + j], h2);
    }
    float o  = h2 * di;
    float o1 = __shfl_down(o, 1);
    if ((j & 1) == 0)
        hs2[node * 8 + (j >> 1)] = __halves2half2(__float2half(o), __float2half(o1));
}

// --- gather layer-2 + fused bias + log_softmax ---
__global__ __launch_bounds__(256) void k_agg2(
    const __half* __restrict__ hs2, const int* __restrict__ ptr,
    const int* __restrict__ csr, const float* __restrict__ dinv,
    const float* __restrict__ b2, float* __restrict__ out, int n)
{
    int t = blockIdx.x * blockDim.x + threadIdx.x;
    int node = t >> 4, j = t & 15;
    if (node >= n) return;
    int s0 = node ? ptr[node - 1] : 0;
    int s1 = ptr[node];
    float sum = __half2float(hs2[node * 16 + j]);    // self-loop
    int e = s0;
    for (; e + 4 <= s1; e += 4) {
        int a0 = csr[e], a1 = csr[e+1], a2 = csr[e+2], a3 = csr[e+3];
        float v0 = __half2float(hs2[a0 * 16 + j]);
        float v1 = __half2float(hs2[a1 * 16 + j]);
        float v2 = __half2float(hs2[a2 * 16 + j]);
        float v3 = __half2float(hs2[a3 * 16 + j]);
        sum += (v0 + v1) + (v2 + v3);
    }
    for (; e < s1; ++e) sum += __half2float(hs2[csr[e] * 16 + j]);

    float v = fmaf(sum, dinv[node], b2[j]);
    float m = v;
    #pragma unroll
    for (int off = 8; off >= 1; off >>= 1) m = fmaxf(m, __shfl_xor(m, off));
    float ex = expf(v - m);
    float s = ex;
    #pragma unroll
    for (int off = 8; off >= 1; off >>= 1) s += __shfl_xor(s, off);
    out[node * 16 + j] = v - m - logf(s);
}

extern "C" void kernel_launch(void* const* d_in, const int* in_sizes, int n_in,
                              void* d_out, int out_size, void* d_ws, size_t ws_size,
                              hipStream_t stream)
{
    const float* x  = (const float*)d_in[0];
    const int*   ei = (const int*)d_in[1];   // [2, E]: row then col
    const float* W1 = (const float*)d_in[2];
    const float* b1 = (const float*)d_in[3];
    const float* W2 = (const float*)d_in[4];
    const float* b2 = (const float*)d_in[5];
    float* out = (float*)d_out;

    const int n = in_sizes[0] / F_IN;        // 100000
    const int E = in_sizes[1] / 2;           // 3.2M
    const int nb = (n + SCAN_B - 1) / SCAN_B;  // 98 (<=128 required by k_scan2)

    // workspace (~20.6 MB):
    // dinv (n f32) | deg (n i32) | ptr (n i32) | bsum (128 i32) | csr (E i32)
    // | hs (n*16 f16) | hs2 (n*16 f16)
    char* ws = (char*)d_ws;
    size_t o = 0;
    #define ALIGN512(s) (((s) + 511) & ~(size_t)511)
    float*   dinv = (float*)(ws + o);   o += ALIGN512((size_t)n * 4);
    int*     deg  = (int*)(ws + o);     o += ALIGN512((size_t)n * 4);
    int*     ptr  = (int*)(ws + o);     o += ALIGN512((size_t)n * 4);
    int*     bsum = (int*)(ws + o);     o += ALIGN512((size_t)128 * 4);
    int*     csr  = (int*)(ws + o);     o += ALIGN512((size_t)E * 4);
    __half2* hs   = (__half2*)(ws + o); o += ALIGN512((size_t)n * 16 * 2);
    __half2* hs2  = (__half2*)(ws + o); o += ALIGN512((size_t)n * 16 * 2);
    #undef ALIGN512

    hipMemsetAsync(deg, 0, (size_t)n * 4, stream);
    k_deg  <<<(E + 255) / 256, 256, 0, stream>>>(ei + E, deg, E);
    k_scan1<<<nb, SCAN_B, 0, stream>>>(deg, ptr, bsum, dinv, n);
    k_scan2<<<1, 128, 0, stream>>>(bsum, nb);
    k_scan3<<<nb, SCAN_B, 0, stream>>>(ptr, bsum, n);
    k_fill <<<(E + 255) / 256, 256, 0, stream>>>(ei, ei + E, ptr, csr, E);

    k_gemm1<<<2048, 256, 0, stream>>>(x, W1, dinv, hs, n);
    k_agg1 <<<(n * 16 + 255) / 256, 256, 0, stream>>>((const __half*)hs, ptr, csr,
                                                      dinv, b1, W2, hs2, n);
    k_agg2 <<<(n * 16 + 255) / 256, 256, 0, stream>>>((const __half*)hs2, ptr, csr,
                                                      dinv, b2, out, n);
}